// Round 4
// baseline (452.091 us; speedup 1.0000x reference)
//
#include <hip/hip_runtime.h>

// Problem constants (B=32, T=8192, D=256, E=16, P=64)
#define NT (32 * 8192)   // 262144 tokens
#define DIM 256
#define NE 16
#define NP 64
#define NCH 64           // token chunks (4096 tokens each)
#define CAPC 352         // per-(expert,chunk) capacity: Binomial(4096,1/16) = 256 +- 15.5; +6.2 sigma

typedef short bf16x8 __attribute__((ext_vector_type(8)));
typedef float f32x4 __attribute__((ext_vector_type(4)));
typedef int i32x4 __attribute__((ext_vector_type(4)));

__device__ __forceinline__ unsigned short f2bf(float f) {
  unsigned int u = __builtin_bit_cast(unsigned int, f);
  u += 0x7fffu + ((u >> 16) & 1u);   // round-to-nearest-even
  return (unsigned short)(u >> 16);
}

// K1: fused prep, 128 blocks (unchanged — ~10 us, not the bottleneck).
//  blocks 0..63:  chunk-local bucketing via LDS counters only.
//  blocks 64..127: W[e][k][n] fp32 -> Wt[e][n][k] bf16 (k-contig, B-frag order).
__global__ void k_prep(const float* __restrict__ W, const int* __restrict__ idx,
                       unsigned short* __restrict__ Wt, int* __restrict__ cnt_ec,
                       int* __restrict__ bucket) {
  int t = threadIdx.x;
  if (blockIdx.x >= 64) {
    int gid = (blockIdx.x - 64) * 256 + t;    // 16384 threads, 16 elems each
    int e = gid >> 10;
    int n = (gid >> 4) & 63;
    int k0 = (gid & 15) << 4;
    const float* src = W + e * (DIM * NP) + n;
    unsigned short* dst = Wt + ((e * NP + n) * DIM + k0);
    #pragma unroll
    for (int j = 0; j < 16; ++j) dst[j] = f2bf(src[(k0 + j) * NP]);
    return;
  }
  __shared__ int cur[NE];
  if (t < NE) cur[t] = 0;
  __syncthreads();
  int c = blockIdx.x;
  int b0 = c * 4096;
  #pragma unroll
  for (int i = 0; i < 16; ++i) {
    int tok = b0 + i * 256 + t;
    int e = idx[tok];
    int pos = atomicAdd(&cur[e], 1);
    if (pos < CAPC) bucket[(e * NCH + c) * CAPC + pos] = tok;
  }
  __syncthreads();
  if (t < NE) cnt_ec[t * NCH + c] = cur[t] < CAPC ? cur[t] : CAPC;
}

// K2 v4b (resubmission — 6 prior attempts all died at container acquire/run;
// full fault-surface audit found no in-kernel mechanism: LDS ops cannot
// VM-fault, all global accesses bounds-verified identical to the passing
// Round-0 pattern, no divergent barrier, no unbounded loop).
// B-operand in 32 KB XOR-swizzled LDS (was 128 VGPRs) -> __launch_bounds__
// (256,4): 4 waves/SIMD, 2x old occupancy, to hide the ~900-cycle A-gather
// latency. One barrier total; tile loop barrier-free. Bias folded into C-in.
// Swizzle: byte addr XOR ((row&7)<<4) on BOTH staging write and read —
// bijective within each 512 B row; wave64 b128 reads land uniformly
// 8 lanes per 16 B slot (minimum aliasing, conflict-free).
__global__ __launch_bounds__(256, 4) void k_gemm(
    const float* __restrict__ x, const unsigned short* __restrict__ Wt,
    const float* __restrict__ bvec, const int* __restrict__ cnt_ec,
    const int* __restrict__ bucket, float* __restrict__ out) {
  int e = blockIdx.x >> 6;
  int slice = blockIdx.x & 63;
  int tid = threadIdx.x;
  int w = tid >> 6;
  int lane = tid & 63;
  int cc = lane & 15, q = lane >> 4;

  __shared__ __align__(16) unsigned short wlds[NP * DIM];  // 32 KB, b128-safe

  // stage Wt[e] (L2-resident, 32 KB) -> LDS, swizzled. 256 thr x 8 x 16 B.
  const unsigned short* wb = Wt + e * NP * DIM;
  #pragma unroll
  for (int it = 0; it < 8; ++it) {
    int lin = (it * 256 + tid) * 16;                    // linear byte offset
    i32x4 v = *(const i32x4*)((const char*)wb + lin);
    int sw = lin ^ (((lin >> 9) & 7) << 4);             // row = lin>>9
    *(i32x4*)((char*)wlds + sw) = v;
  }

  float bias[4];
  #pragma unroll
  for (int nf = 0; nf < 4; ++nf) bias[nf] = bvec[e * NP + nf * 16 + cc];

  // per-nf swizzled LDS read base: linear = n*512 + ks*64 + q*16, then
  // XOR (n&7)<<4 applied AFTER adding ks<<6 (same involution as the write;
  // XOR bits 4-6 overlap the ks<<6 bit-6 term, so order matters).
  int base0[4], swz[4];
  #pragma unroll
  for (int nf = 0; nf < 4; ++nf) {
    int n = nf * 16 + cc;
    base0[nf] = (n << 9) + (q << 4);
    swz[nf] = (n & 7) << 4;
  }

  __syncthreads();   // only barrier; tile loop below is barrier-free

  int s = slice * 4 + w;            // 0..255
  int c = s >> 2;                   // chunk
  int sub = s & 3;

  int rows_ec = cnt_ec[e * NCH + c];
  int ntiles = (rows_ec + 15) >> 4;
  const int* bkt = bucket + (e * NCH + c) * CAPC;

  for (int rt = sub; rt < ntiles; rt += 4) {
    int r0 = rt << 4;
    int rows = rows_ec - r0;
    if (rows > 16) rows = 16;

    // A-row pointer for this lane (m = cc); clamp tail rows to row 0
    int myr = cc < rows ? cc : 0;
    int tok = bkt[r0 + myr];
    const float* xr = x + (long)tok * DIM + q * 8;

    // issue the full A-tile's loads (16 x dwordx4 per lane, all in flight)
    f32x4 va[16];
    #pragma unroll
    for (int ks = 0; ks < 8; ++ks) {
      va[2 * ks]     = *(const f32x4*)(xr + ks * 32);
      va[2 * ks + 1] = *(const f32x4*)(xr + ks * 32 + 4);
    }

    f32x4 acc[4];
    #pragma unroll
    for (int nf = 0; nf < 4; ++nf)
      acc[nf] = (f32x4){bias[nf], bias[nf], bias[nf], bias[nf]};

    #pragma unroll
    for (int ks = 0; ks < 8; ++ks) {
      bf16x8 a;
      #pragma unroll
      for (int j = 0; j < 4; ++j) {
        a[j]     = (short)f2bf(va[2 * ks][j]);
        a[4 + j] = (short)f2bf(va[2 * ks + 1][j]);
      }
      #pragma unroll
      for (int nf = 0; nf < 4; ++nf) {
        const bf16x8 bf = *(const bf16x8*)(
            (const char*)wlds + ((base0[nf] + (ks << 6)) ^ swz[nf]));
        acc[nf] = __builtin_amdgcn_mfma_f32_16x16x32_bf16(a, bf, acc[nf], 0, 0, 0);
      }
    }

    // epilogue: C/D layout col = lane&15, row = q*4+reg; scatter by token id
    #pragma unroll
    for (int r = 0; r < 4; ++r) {
      int m = q * 4 + r;
      if (m < rows) {
        int tk = bkt[r0 + m];
        float* orow = out + (long)tk * NP + cc;
        #pragma unroll
        for (int nf = 0; nf < 4; ++nf) orow[nf * 16] = acc[nf][r];
      }
    }
  }
}

extern "C" void kernel_launch(void* const* d_in, const int* in_sizes, int n_in,
                              void* d_out, int out_size, void* d_ws, size_t ws_size,
                              hipStream_t stream) {
  const float* x = (const float*)d_in[0];
  const float* W = (const float*)d_in[1];
  const float* b = (const float*)d_in[2];
  const int* idx = (const int*)d_in[3];
  float* out = (float*)d_out;

  int* ws = (int*)d_ws;
  int* cnt_ec = ws;                                    // NE*NCH = 1024 ints
  int* bucket = ws + 1024;                             // NE*NCH*CAPC ints (1.41 MB)
  unsigned short* Wt = (unsigned short*)(ws + 1024 + NE * NCH * CAPC);  // 512 KB

  k_prep<<<128, 256, 0, stream>>>(W, idx, Wt, cnt_ec, bucket);
  k_gemm<<<NE * 64, 256, 0, stream>>>(x, Wt, b, cnt_ec, bucket, out);
}

// Round 5
// 402.885 us; speedup vs baseline: 1.1221x; 1.1221x over previous
//
#include <hip/hip_runtime.h>

// Problem constants (B=32, T=8192, D=256, E=16, P=64)
#define NT (32 * 8192)   // 262144 tokens
#define DIM 256
#define NE 16
#define NP 64
#define NCH 64           // token chunks (4096 tokens each)
#define CAPC 352         // per-(expert,chunk) capacity: Binomial(4096,1/16) = 256 +- 15.5; +6.2 sigma

typedef short bf16x8 __attribute__((ext_vector_type(8)));
typedef float f32x4 __attribute__((ext_vector_type(4)));
typedef int i32x4 __attribute__((ext_vector_type(4)));

__device__ __forceinline__ unsigned short f2bf(float f) {
  unsigned int u = __builtin_bit_cast(unsigned int, f);
  u += 0x7fffu + ((u >> 16) & 1u);   // round-to-nearest-even
  return (unsigned short)(u >> 16);
}

// K1: fused prep, 128 blocks (unchanged — not the bottleneck).
__global__ void k_prep(const float* __restrict__ W, const int* __restrict__ idx,
                       unsigned short* __restrict__ Wt, int* __restrict__ cnt_ec,
                       int* __restrict__ bucket) {
  int t = threadIdx.x;
  if (blockIdx.x >= 64) {
    int gid = (blockIdx.x - 64) * 256 + t;    // 16384 threads, 16 elems each
    int e = gid >> 10;
    int n = (gid >> 4) & 63;
    int k0 = (gid & 15) << 4;
    const float* src = W + e * (DIM * NP) + n;
    unsigned short* dst = Wt + ((e * NP + n) * DIM + k0);
    #pragma unroll
    for (int j = 0; j < 16; ++j) dst[j] = f2bf(src[(k0 + j) * NP]);
    return;
  }
  __shared__ int cur[NE];
  if (t < NE) cur[t] = 0;
  __syncthreads();
  int c = blockIdx.x;
  int b0 = c * 4096;
  #pragma unroll
  for (int i = 0; i < 16; ++i) {
    int tok = b0 + i * 256 + t;
    int e = idx[tok];
    int pos = atomicAdd(&cur[e], 1);
    if (pos < CAPC) bucket[(e * NCH + c) * CAPC + pos] = tok;
  }
  __syncthreads();
  if (t < NE) cnt_ec[t * NCH + c] = cur[t] < CAPC ? cur[t] : CAPC;
}

// K2 v5: v4b + burst-pinning. v4b's counters (VGPR=64, MfmaUtil 1.9%,
// VALUBusy 3.8%, HBM 30%) showed the compiler sank the 16-load A-burst
// into its uses -> ~8 dependent HBM round-trips per tile. Fix:
//  (a) sched_barrier(0) right after the burst — all 16 gather loads issue
//      before any convert/MFMA consumes them (restores Round-0's ILP);
//  (b) next tile's gather token + this tile's 4 store-address tokens are
//      loaded immediately after the burst, so their L2 latency hides under
//      the convert/MFMA phase instead of serializing the loop.
// B stays in 32 KB XOR-swizzled LDS; (256,4) keeps VGPR<=128 so all
// 4 blocks/CU (grid cap) remain resident.
__global__ __launch_bounds__(256, 4) void k_gemm(
    const float* __restrict__ x, const unsigned short* __restrict__ Wt,
    const float* __restrict__ bvec, const int* __restrict__ cnt_ec,
    const int* __restrict__ bucket, float* __restrict__ out) {
  int e = blockIdx.x >> 6;
  int slice = blockIdx.x & 63;
  int tid = threadIdx.x;
  int w = tid >> 6;
  int lane = tid & 63;
  int cc = lane & 15, q = lane >> 4;

  __shared__ __align__(16) unsigned short wlds[NP * DIM];  // 32 KB, b128-safe

  // stage Wt[e] (L2-resident, 32 KB) -> LDS, swizzled. 256 thr x 8 x 16 B.
  const unsigned short* wb = Wt + e * NP * DIM;
  #pragma unroll
  for (int it = 0; it < 8; ++it) {
    int lin = (it * 256 + tid) * 16;                    // linear byte offset
    i32x4 v = *(const i32x4*)((const char*)wb + lin);
    int sw = lin ^ (((lin >> 9) & 7) << 4);             // row = lin>>9
    *(i32x4*)((char*)wlds + sw) = v;
  }

  float bias[4];
  #pragma unroll
  for (int nf = 0; nf < 4; ++nf) bias[nf] = bvec[e * NP + nf * 16 + cc];

  // swizzled LDS read base: linear = n*512 + ks*64 + q*16, XOR (n&7)<<4
  // applied AFTER adding ks<<6 (same involution as the write).
  int base0[4], swz[4];
  #pragma unroll
  for (int nf = 0; nf < 4; ++nf) {
    int n = nf * 16 + cc;
    base0[nf] = (n << 9) + (q << 4);
    swz[nf] = (n & 7) << 4;
  }

  __syncthreads();   // only barrier; tile loop below is barrier-free

  int s = slice * 4 + w;            // 0..255
  int c = s >> 2;                   // chunk
  int sub = s & 3;

  int rows_ec = cnt_ec[e * NCH + c];
  int ntiles = (rows_ec + 15) >> 4;
  const int* bkt = bucket + (e * NCH + c) * CAPC;

  // first tile's gather token (serial, once)
  int tok = 0;
  if (sub < ntiles) {
    int r0f = sub << 4;
    int rowsf = rows_ec - r0f; if (rowsf > 16) rowsf = 16;
    tok = bkt[r0f + (cc < rowsf ? cc : 0)];
  }

  for (int rt = sub; rt < ntiles; rt += 4) {
    int r0 = rt << 4;
    int rows = rows_ec - r0;
    if (rows > 16) rows = 16;

    const float* xr = x + (long)tok * DIM + q * 8;

    // issue the full A-tile's gather (16 x dwordx4 per lane, all in flight)
    f32x4 va[16];
    #pragma unroll
    for (int ks = 0; ks < 8; ++ks) {
      va[2 * ks]     = *(const f32x4*)(xr + ks * 32);
      va[2 * ks + 1] = *(const f32x4*)(xr + ks * 32 + 4);
    }
    // pin the burst: nothing below may be hoisted above, loads may not sink
    __builtin_amdgcn_sched_barrier(0);

    // L2 prefetches that hide under the convert/MFMA phase:
    // next tile's gather token...
    int rt2 = rt + 4;
    int r02 = rt2 << 4;
    int rows2 = rows_ec - r02;
    int tok_next = bkt[rt2 < ntiles ? (r02 + (cc < rows2 ? cc : 0)) : 0];
    // ...and this tile's 4 store-address tokens (index clamped in-tile)
    int tkpre[4];
    #pragma unroll
    for (int r = 0; r < 4; ++r) {
      int m = q * 4 + r;
      tkpre[r] = bkt[m < rows ? r0 + m : r0];
    }

    f32x4 acc[4];
    #pragma unroll
    for (int nf = 0; nf < 4; ++nf)
      acc[nf] = (f32x4){bias[nf], bias[nf], bias[nf], bias[nf]};

    #pragma unroll
    for (int ks = 0; ks < 8; ++ks) {
      bf16x8 a;
      #pragma unroll
      for (int j = 0; j < 4; ++j) {
        a[j]     = (short)f2bf(va[2 * ks][j]);
        a[4 + j] = (short)f2bf(va[2 * ks + 1][j]);
      }
      #pragma unroll
      for (int nf = 0; nf < 4; ++nf) {
        const bf16x8 bf = *(const bf16x8*)(
            (const char*)wlds + ((base0[nf] + (ks << 6)) ^ swz[nf]));
        acc[nf] = __builtin_amdgcn_mfma_f32_16x16x32_bf16(a, bf, acc[nf], 0, 0, 0);
      }
    }

    // epilogue: C/D layout col = lane&15, row = q*4+reg; scatter by token id
    #pragma unroll
    for (int r = 0; r < 4; ++r) {
      int m = q * 4 + r;
      if (m < rows) {
        float* orow = out + (long)tkpre[r] * NP + cc;
        #pragma unroll
        for (int nf = 0; nf < 4; ++nf) orow[nf * 16] = acc[nf][r];
      }
    }
    tok = tok_next;
  }
}

extern "C" void kernel_launch(void* const* d_in, const int* in_sizes, int n_in,
                              void* d_out, int out_size, void* d_ws, size_t ws_size,
                              hipStream_t stream) {
  const float* x = (const float*)d_in[0];
  const float* W = (const float*)d_in[1];
  const float* b = (const float*)d_in[2];
  const int* idx = (const int*)d_in[3];
  float* out = (float*)d_out;

  int* ws = (int*)d_ws;
  int* cnt_ec = ws;                                    // NE*NCH = 1024 ints
  int* bucket = ws + 1024;                             // NE*NCH*CAPC ints (1.41 MB)
  unsigned short* Wt = (unsigned short*)(ws + 1024 + NE * NCH * CAPC);  // 512 KB

  k_prep<<<128, 256, 0, stream>>>(W, idx, Wt, cnt_ec, bucket);
  k_gemm<<<NE * 64, 256, 0, stream>>>(x, Wt, b, cnt_ec, bucket, out);
}

// Round 6
// 390.073 us; speedup vs baseline: 1.1590x; 1.0328x over previous
//
#include <hip/hip_runtime.h>

// Problem constants (B=32, T=8192, D=256, E=16, P=64)
#define NT (32 * 8192)   // 262144 tokens
#define DIM 256
#define NE 16
#define NP 64
#define NCH 64           // token chunks (4096 tokens each)
#define CAPC 352         // per-(expert,chunk) capacity: Binomial(4096,1/16) = 256 +- 15.5; +6.2 sigma

typedef short bf16x8 __attribute__((ext_vector_type(8)));
typedef float f32x4 __attribute__((ext_vector_type(4)));
typedef int i32x4 __attribute__((ext_vector_type(4)));

__device__ __forceinline__ unsigned short f2bf(float f) {
  unsigned int u = __builtin_bit_cast(unsigned int, f);
  u += 0x7fffu + ((u >> 16) & 1u);   // round-to-nearest-even
  return (unsigned short)(u >> 16);
}

// K1: fused prep, 128 blocks (unchanged — not the bottleneck).
__global__ void k_prep(const float* __restrict__ W, const int* __restrict__ idx,
                       unsigned short* __restrict__ Wt, int* __restrict__ cnt_ec,
                       int* __restrict__ bucket) {
  int t = threadIdx.x;
  if (blockIdx.x >= 64) {
    int gid = (blockIdx.x - 64) * 256 + t;    // 16384 threads, 16 elems each
    int e = gid >> 10;
    int n = (gid >> 4) & 63;
    int k0 = (gid & 15) << 4;
    const float* src = W + e * (DIM * NP) + n;
    unsigned short* dst = Wt + ((e * NP + n) * DIM + k0);
    #pragma unroll
    for (int j = 0; j < 16; ++j) dst[j] = f2bf(src[(k0 + j) * NP]);
    return;
  }
  __shared__ int cur[NE];
  if (t < NE) cur[t] = 0;
  __syncthreads();
  int c = blockIdx.x;
  int b0 = c * 4096;
  #pragma unroll
  for (int i = 0; i < 16; ++i) {
    int tok = b0 + i * 256 + t;
    int e = idx[tok];
    int pos = atomicAdd(&cur[e], 1);
    if (pos < CAPC) bucket[(e * NCH + c) * CAPC + pos] = tok;
  }
  __syncthreads();
  if (t < NE) cnt_ec[t * NCH + c] = cur[t] < CAPC ? cur[t] : CAPC;
}

// K2 v6: v5 + column-permuted accumulators for full-line stores.
// v4b counters showed WRITE_SIZE = 136 MB vs 67 MB ideal (2.08x): the 4 B/lane
// epilogue stores emit 64 B segments, so each 128 B line reaches HBM as two
// partial writes. Fix: accumulator nf / lane cc now computes pixel n = 4*cc+nf
// (a free choice — only the B-fragment LDS read base and bias index change),
// so each lane's 4 acc values are 4 CONSECUTIVE floats -> one
// global_store_dwordx4 per r: 4 full 256 B rows per instruction, fully
// contiguous. Bank histogram of the new LDS read pattern verified uniform
// (8 dword-accesses/bank = wave64 b128 floor) under the same XOR swizzle.
// Everything else identical to v5 (burst pin via sched_barrier, token/store
// prefetch, (256,4), 32 KB swizzled LDS B).
__global__ __launch_bounds__(256, 4) void k_gemm(
    const float* __restrict__ x, const unsigned short* __restrict__ Wt,
    const float* __restrict__ bvec, const int* __restrict__ cnt_ec,
    const int* __restrict__ bucket, float* __restrict__ out) {
  int e = blockIdx.x >> 6;
  int slice = blockIdx.x & 63;
  int tid = threadIdx.x;
  int w = tid >> 6;
  int lane = tid & 63;
  int cc = lane & 15, q = lane >> 4;

  __shared__ __align__(16) unsigned short wlds[NP * DIM];  // 32 KB, b128-safe

  // stage Wt[e] (L2-resident, 32 KB) -> LDS, swizzled. 256 thr x 8 x 16 B.
  const unsigned short* wb = Wt + e * NP * DIM;
  #pragma unroll
  for (int it = 0; it < 8; ++it) {
    int lin = (it * 256 + tid) * 16;                    // linear byte offset
    i32x4 v = *(const i32x4*)((const char*)wb + lin);
    int sw = lin ^ (((lin >> 9) & 7) << 4);             // row = lin>>9
    *(i32x4*)((char*)wlds + sw) = v;
  }

  // bias: lane cc owns pixels 4cc..4cc+3 -> single float4 load
  f32x4 bias4 = *(const f32x4*)(bvec + e * NP + 4 * cc);

  // swizzled LDS read base for pixel n = 4*cc + nf:
  // linear = n*512 + ks*64 + q*16, XOR (n&7)<<4 applied AFTER adding ks<<6.
  int base0[4], swz[4];
  #pragma unroll
  for (int nf = 0; nf < 4; ++nf) {
    int n = 4 * cc + nf;
    base0[nf] = (n << 9) + (q << 4);
    swz[nf] = (n & 7) << 4;
  }

  __syncthreads();   // only barrier; tile loop below is barrier-free

  int s = slice * 4 + w;            // 0..255
  int c = s >> 2;                   // chunk
  int sub = s & 3;

  int rows_ec = cnt_ec[e * NCH + c];
  int ntiles = (rows_ec + 15) >> 4;
  const int* bkt = bucket + (e * NCH + c) * CAPC;

  // first tile's gather token (serial, once)
  int tok = 0;
  if (sub < ntiles) {
    int r0f = sub << 4;
    int rowsf = rows_ec - r0f; if (rowsf > 16) rowsf = 16;
    tok = bkt[r0f + (cc < rowsf ? cc : 0)];
  }

  for (int rt = sub; rt < ntiles; rt += 4) {
    int r0 = rt << 4;
    int rows = rows_ec - r0;
    if (rows > 16) rows = 16;

    const float* xr = x + (long)tok * DIM + q * 8;

    // issue the full A-tile's gather (16 x dwordx4 per lane, all in flight)
    f32x4 va[16];
    #pragma unroll
    for (int ks = 0; ks < 8; ++ks) {
      va[2 * ks]     = *(const f32x4*)(xr + ks * 32);
      va[2 * ks + 1] = *(const f32x4*)(xr + ks * 32 + 4);
    }
    // pin the burst: nothing below may be hoisted above, loads may not sink
    __builtin_amdgcn_sched_barrier(0);

    // L2 prefetches that hide under the convert/MFMA phase:
    // next tile's gather token...
    int rt2 = rt + 4;
    int r02 = rt2 << 4;
    int rows2 = rows_ec - r02;
    int tok_next = bkt[rt2 < ntiles ? (r02 + (cc < rows2 ? cc : 0)) : 0];
    // ...and this tile's 4 store-address tokens (index clamped in-tile)
    int tkpre[4];
    #pragma unroll
    for (int r = 0; r < 4; ++r) {
      int m = q * 4 + r;
      tkpre[r] = bkt[m < rows ? r0 + m : r0];
    }

    f32x4 acc[4];
    #pragma unroll
    for (int nf = 0; nf < 4; ++nf)
      acc[nf] = (f32x4){bias4[nf], bias4[nf], bias4[nf], bias4[nf]};

    #pragma unroll
    for (int ks = 0; ks < 8; ++ks) {
      bf16x8 a;
      #pragma unroll
      for (int j = 0; j < 4; ++j) {
        a[j]     = (short)f2bf(va[2 * ks][j]);
        a[4 + j] = (short)f2bf(va[2 * ks + 1][j]);
      }
      #pragma unroll
      for (int nf = 0; nf < 4; ++nf) {
        const bf16x8 bf = *(const bf16x8*)(
            (const char*)wlds + ((base0[nf] + (ks << 6)) ^ swz[nf]));
        acc[nf] = __builtin_amdgcn_mfma_f32_16x16x32_bf16(a, bf, acc[nf], 0, 0, 0);
      }
    }

    // epilogue: row m = q*4+r; lane cc owns pixels 4cc..4cc+3 -> dwordx4.
    // Each instruction writes 4 full 256 B rows, fully contiguous.
    #pragma unroll
    for (int r = 0; r < 4; ++r) {
      int m = q * 4 + r;
      if (m < rows) {
        f32x4 v = {acc[0][r], acc[1][r], acc[2][r], acc[3][r]};
        *(f32x4*)(out + (long)tkpre[r] * NP + 4 * cc) = v;
      }
    }
    tok = tok_next;
  }
}

extern "C" void kernel_launch(void* const* d_in, const int* in_sizes, int n_in,
                              void* d_out, int out_size, void* d_ws, size_t ws_size,
                              hipStream_t stream) {
  const float* x = (const float*)d_in[0];
  const float* W = (const float*)d_in[1];
  const float* b = (const float*)d_in[2];
  const int* idx = (const int*)d_in[3];
  float* out = (float*)d_out;

  int* ws = (int*)d_ws;
  int* cnt_ec = ws;                                    // NE*NCH = 1024 ints
  int* bucket = ws + 1024;                             // NE*NCH*CAPC ints (1.41 MB)
  unsigned short* Wt = (unsigned short*)(ws + 1024 + NE * NCH * CAPC);  // 512 KB

  k_prep<<<128, 256, 0, stream>>>(W, idx, Wt, cnt_ec, bucket);
  k_gemm<<<NE * 64, 256, 0, stream>>>(x, Wt, b, cnt_ec, bucket, out);
}